// Round 14
// baseline (87.349 us; speedup 1.0000x reference)
//
#include <hip/hip_runtime.h>
#include <hip/hip_bf16.h>

#define BATCH 8
#define NDIM 2048
#define FDIM 256
#define CH 32   // row-chunks for column-sum partials (64 rows each)

typedef float f32x4 __attribute__((ext_vector_type(4)));
typedef short bf16x8 __attribute__((ext_vector_type(8)));
typedef short bf16x4 __attribute__((ext_vector_type(4)));

// hardware RNE convert (lowers to v_cvt_pk_bf16_f32 when paired)
__device__ __forceinline__ short f2bf(float f) {
  __hip_bfloat16 h = __float2bfloat16(f);
  short s;
  __builtin_memcpy(&s, &h, 2);
  return s;
}

__device__ __forceinline__ void gload_lds16(const void* g, void* l) {
  __builtin_amdgcn_global_load_lds(
      (const __attribute__((address_space(1))) void*)g,
      (__attribute__((address_space(3))) void*)l, 16, 0, 0);
}

// ---- Kernel 1: colsum partials (blocks 0..511) + Wt transpose (512..527) --
__global__ __launch_bounds__(256) void k_colsum(const float* __restrict__ adj,
                                                float* __restrict__ part,
                                                const float* __restrict__ w,
                                                short* __restrict__ wt) {
  int bid = blockIdx.x;
  int t = threadIdx.x;
  if (bid < 512) {
    int cb = bid & 1;
    int ch = (bid >> 1) & (CH - 1);
    int b = bid >> 6;
    int col = cb * 1024 + t * 4;
    const float* p = adj + (size_t)b * NDIM * NDIM + (size_t)(ch * 64) * NDIM + col;
    f32x4 acc = {0.f, 0.f, 0.f, 0.f};
#pragma unroll 8
    for (int i = 0; i < 64; ++i) acc += *(const f32x4*)(p + (size_t)i * NDIM);
    *(f32x4*)(part + (size_t)(b * CH + ch) * NDIM + col) = acc;
  } else {
    __shared__ float tile[64][65];
    int bb = bid - 512;
    int bx = bb & 3, by = bb >> 2;
    int f0 = by * 64, o0 = bx * 64;
    int c4 = 4 * (t & 15);
#pragma unroll
    for (int q = 0; q < 4; ++q) {
      int r = (t >> 4) + 16 * q;
      f32x4 v = *(const f32x4*)(w + (size_t)(f0 + r) * FDIM + o0 + c4);
#pragma unroll
      for (int i = 0; i < 4; ++i) tile[r][c4 + i] = v[i];
    }
    __syncthreads();
#pragma unroll
    for (int q = 0; q < 4; ++q) {
      int r = (t >> 4) + 16 * q;
      bf16x4 pk;
#pragma unroll
      for (int i = 0; i < 4; ++i) pk[i] = f2bf(tile[c4 + i][r]);
      *(bf16x4*)(wt + (size_t)(o0 + r) * FDIM + f0 + c4) = pk;
    }
  }
}

// ---- Kernel 2: St[b][o][m] = bf16(d[b][m] * (X @ W)[m][o]) ----
// (unchanged from R13 — proven)
__global__ __launch_bounds__(512) void k_support(const float* __restrict__ in,
                                                 const short* __restrict__ wt,
                                                 const float* __restrict__ part,
                                                 float* __restrict__ dnorm,
                                                 short* __restrict__ st) {
  __shared__ float Alf[3][64 * 64];   // 3 x 16 KB (f32 A tiles)
  __shared__ short Bl[3][256 * 64];   // 3 x 32 KB (bf16 B tiles)
  __shared__ float dnLds[64];
  int t = threadIdx.x, lane = t & 63, w = t >> 6;
  int wm = w & 1, wn = w >> 1;
  int b = blockIdx.x & 7;
  int m0 = (blockIdx.x >> 3) * 64;
  const float* inb = in + ((size_t)b * NDIM + m0) * FDIM;

  if (t < 64) {
    float s = 0.f;
#pragma unroll
    for (int c = 0; c < CH; ++c) s += part[(size_t)(b * CH + c) * NDIM + m0 + t];
    float dv = rsqrtf(s);
    dnLds[t] = dv;
    dnorm[b * NDIM + m0 + t] = dv;
  }
  asm volatile("s_waitcnt vmcnt(0)" ::: "memory");

  int s0 = t, s1 = 512 + t;
  int r0 = s0 >> 4, c0 = (s0 & 15) ^ ((r0 & 7) << 1);
  int r1 = s1 >> 4, c1 = (s1 & 15) ^ ((r1 & 7) << 1);
  const float* a0s = inb + (size_t)r0 * FDIM + c0 * 4;
  const float* a1s = inb + (size_t)r1 * FDIM + c1 * 4;
  int arow = t >> 3;
  int schk = (t & 7) ^ (arow & 7);
  const short* bsrc = wt + (size_t)arow * FDIM + 8 * schk;

  f32x4 acc[2][4];
#pragma unroll
  for (int m = 0; m < 2; ++m)
#pragma unroll
    for (int n = 0; n < 4; ++n) acc[m][n] = {0.f, 0.f, 0.f, 0.f};

  int lr = lane & 15, kg = lane >> 4, sw = lane & 7, sw2 = (lane & 7) << 1;

  auto stage = [&](int k, int bp) {
    size_t ko = (size_t)k * 64;
    gload_lds16(a0s + ko, &Alf[bp][s0 * 4]);
    gload_lds16(a1s + ko, &Alf[bp][s1 * 4]);
#pragma unroll
    for (int i = 0; i < 4; ++i)
      gload_lds16(bsrc + (size_t)(i * 64) * FDIM + ko, &Bl[bp][(i * 512 + t) * 8]);
  };

  auto body = [&](int it, int bc, int bp, int mode) {
    if (mode == 0) {
      stage(it + 2, bp);
      asm volatile("s_waitcnt vmcnt(12)" ::: "memory");
    } else if (mode == 1) {
      asm volatile("s_waitcnt vmcnt(6)" ::: "memory");
    } else {
      asm volatile("s_waitcnt vmcnt(0)" ::: "memory");
    }
    __builtin_amdgcn_s_barrier();
    asm volatile("" ::: "memory");
    __builtin_amdgcn_sched_barrier(0);
#pragma unroll
    for (int h = 0; h < 2; ++h) {
      int gk = h * 4 + kg;
      bf16x8 af[2];
#pragma unroll
      for (int mf = 0; mf < 2; ++mf) {
        const float* ap = &Alf[bc][(wm * 32 + mf * 16 + lr) * 64 + (((2 * gk) ^ sw2) * 4)];
        f32x4 lo = *(const f32x4*)ap;
        f32x4 hi = *(const f32x4*)(ap + 4);
#pragma unroll
        for (int j = 0; j < 4; ++j) { af[mf][j] = f2bf(lo[j]); af[mf][4 + j] = f2bf(hi[j]); }
      }
      int kc = (gk ^ sw) * 8;
      bf16x8 bv0 = *(const bf16x8*)&Bl[bc][(wn * 64 + lr) * 64 + kc];
      bf16x8 bv1 = *(const bf16x8*)&Bl[bc][(wn * 64 + 16 + lr) * 64 + kc];
      bf16x8 bv2 = *(const bf16x8*)&Bl[bc][(wn * 64 + 32 + lr) * 64 + kc];
      bf16x8 bv3 = *(const bf16x8*)&Bl[bc][(wn * 64 + 48 + lr) * 64 + kc];
      acc[0][0] = __builtin_amdgcn_mfma_f32_16x16x32_bf16(af[0], bv0, acc[0][0], 0, 0, 0);
      acc[0][1] = __builtin_amdgcn_mfma_f32_16x16x32_bf16(af[0], bv1, acc[0][1], 0, 0, 0);
      acc[0][2] = __builtin_amdgcn_mfma_f32_16x16x32_bf16(af[0], bv2, acc[0][2], 0, 0, 0);
      acc[0][3] = __builtin_amdgcn_mfma_f32_16x16x32_bf16(af[0], bv3, acc[0][3], 0, 0, 0);
      acc[1][0] = __builtin_amdgcn_mfma_f32_16x16x32_bf16(af[1], bv0, acc[1][0], 0, 0, 0);
      acc[1][1] = __builtin_amdgcn_mfma_f32_16x16x32_bf16(af[1], bv1, acc[1][1], 0, 0, 0);
      acc[1][2] = __builtin_amdgcn_mfma_f32_16x16x32_bf16(af[1], bv2, acc[1][2], 0, 0, 0);
      acc[1][3] = __builtin_amdgcn_mfma_f32_16x16x32_bf16(af[1], bv3, acc[1][3], 0, 0, 0);
    }
    asm volatile("s_waitcnt lgkmcnt(0)" ::: "memory");
    __builtin_amdgcn_s_barrier();
    asm volatile("" ::: "memory");
  };

  stage(0, 0);
  stage(1, 1);
  body(0, 0, 2, 0);
  body(1, 1, 0, 0);
  body(2, 2, 1, 1);
  body(3, 0, 2, 2);

#pragma unroll
  for (int mf = 0; mf < 2; ++mf) {
    int rloc = wm * 32 + mf * 16 + kg * 4;
    int row = m0 + rloc;
    float dm[4];
#pragma unroll
    for (int j = 0; j < 4; ++j) dm[j] = dnLds[rloc + j];
#pragma unroll
    for (int nf = 0; nf < 4; ++nf) {
      int col = wn * 64 + nf * 16 + lr;
      bf16x4 pk;
#pragma unroll
      for (int j = 0; j < 4; ++j) pk[j] = f2bf(acc[mf][nf][j] * dm[j]);
      *(bf16x4*)(st + ((size_t)(b * FDIM + col)) * NDIM + row) = pk;
    }
  }
}

// ---- Kernel 3: out = d_n * (adj @ St^T) + bias ----
// BK=32 variant of the proven skeleton: buffers 8KB(A f32)+16KB(B) x3 = 72KB
// -> 2 blocks/CU (TLP covers rendezvous stalls) WITH depth-2 counted vmcnt.
// 64 bodies x 8 MFMA. A: 8 chunks/row XOR row&7 (2-way, free). B: 4
// chunks/row XOR row&3 (4-way on 4 reads/body, negligible).
__global__ __launch_bounds__(512, 4) void k_main(const float* __restrict__ adj,
                                                 const short* __restrict__ st,
                                                 const float* __restrict__ dnorm,
                                                 const float* __restrict__ bias,
                                                 float* __restrict__ out) {
  __shared__ float Alf[3][64 * 32];   // 3 x 8 KB  (f32 A tiles, BK=32)
  __shared__ short Bl[3][256 * 32];   // 3 x 16 KB (bf16 B tiles)
  int t = threadIdx.x, lane = t & 63, w = t >> 6;
  int wm = w & 1, wn = w >> 1;
  int b = blockIdx.x & 7;
  int n0 = (blockIdx.x >> 3) * 64;
  const float* ab = adj + ((size_t)b * NDIM + n0) * NDIM;
  const short* stb = st + (size_t)b * FDIM * NDIM;

  // A stage: 512 chunks(16B)/tile, 1 gll/thread: row=t>>3, chunk c=t&7,
  // src chunk inverse-swizzled c^(row&7); LDS linear.
  int rA = t >> 3, cA = (t & 7) ^ ((t >> 3) & 7);
  const float* aS = ab + (size_t)rA * NDIM + cA * 4;
  // B stage: 1024 chunks/tile, 2 gll/thread: slot s=i*512+t -> row=s>>2,
  // chunk c=(s&3)^(row&3); LDS linear.
  int sB0 = t, sB1 = 512 + t;
  int rB0 = sB0 >> 2, cB0 = (sB0 & 3) ^ (rB0 & 3);
  int rB1 = sB1 >> 2, cB1 = (sB1 & 3) ^ (rB1 & 3);
  const short* bS0 = stb + (size_t)rB0 * NDIM + cB0 * 8;
  const short* bS1 = stb + (size_t)rB1 * NDIM + cB1 * 8;

  f32x4 acc[2][4];
#pragma unroll
  for (int m = 0; m < 2; ++m)
#pragma unroll
    for (int n = 0; n < 4; ++n) acc[m][n] = {0.f, 0.f, 0.f, 0.f};

  int lr = lane & 15, kg = lane >> 4;

  auto stage = [&](int k, int bp) {
    size_t ko = (size_t)k * 32;
    gload_lds16(aS + ko, &Alf[bp][t * 4]);
    gload_lds16(bS0 + ko, &Bl[bp][sB0 * 8]);
    gload_lds16(bS1 + ko, &Bl[bp][sB1 * 8]);
  };

  auto body = [&](int it, int bc, int bp, int mode) {
    if (mode == 0) {
      stage(it + 2, bp);
      asm volatile("s_waitcnt vmcnt(6)" ::: "memory");
    } else if (mode == 1) {
      asm volatile("s_waitcnt vmcnt(3)" ::: "memory");
    } else {
      asm volatile("s_waitcnt vmcnt(0)" ::: "memory");
    }
    __builtin_amdgcn_s_barrier();
    asm volatile("" ::: "memory");
    __builtin_amdgcn_sched_barrier(0);
    bf16x8 af[2];
#pragma unroll
    for (int mf = 0; mf < 2; ++mf) {
      int row = wm * 32 + mf * 16 + lr;
      int ch0 = (2 * kg) ^ (row & 7), ch1 = (2 * kg + 1) ^ (row & 7);
      f32x4 lo = *(const f32x4*)&Alf[bc][row * 32 + ch0 * 4];
      f32x4 hi = *(const f32x4*)&Alf[bc][row * 32 + ch1 * 4];
#pragma unroll
      for (int j = 0; j < 4; ++j) { af[mf][j] = f2bf(lo[j]); af[mf][4 + j] = f2bf(hi[j]); }
    }
    bf16x8 bv[4];
#pragma unroll
    for (int nf = 0; nf < 4; ++nf) {
      int row = wn * 64 + nf * 16 + lr;
      bv[nf] = *(const bf16x8*)&Bl[bc][row * 32 + (kg ^ (row & 3)) * 8];
    }
    acc[0][0] = __builtin_amdgcn_mfma_f32_16x16x32_bf16(af[0], bv[0], acc[0][0], 0, 0, 0);
    acc[0][1] = __builtin_amdgcn_mfma_f32_16x16x32_bf16(af[0], bv[1], acc[0][1], 0, 0, 0);
    acc[0][2] = __builtin_amdgcn_mfma_f32_16x16x32_bf16(af[0], bv[2], acc[0][2], 0, 0, 0);
    acc[0][3] = __builtin_amdgcn_mfma_f32_16x16x32_bf16(af[0], bv[3], acc[0][3], 0, 0, 0);
    acc[1][0] = __builtin_amdgcn_mfma_f32_16x16x32_bf16(af[1], bv[0], acc[1][0], 0, 0, 0);
    acc[1][1] = __builtin_amdgcn_mfma_f32_16x16x32_bf16(af[1], bv[1], acc[1][1], 0, 0, 0);
    acc[1][2] = __builtin_amdgcn_mfma_f32_16x16x32_bf16(af[1], bv[2], acc[1][2], 0, 0, 0);
    acc[1][3] = __builtin_amdgcn_mfma_f32_16x16x32_bf16(af[1], bv[3], acc[1][3], 0, 0, 0);
    asm volatile("s_waitcnt lgkmcnt(0)" ::: "memory");
    __builtin_amdgcn_s_barrier();
    asm volatile("" ::: "memory");
  };

  stage(0, 0);
  stage(1, 1);
  // bodies 0..59 in triples (mode 0), then 60,61 (mode 0), 62 (mode 1), 63 (mode 2)
  for (int itb = 0; itb < 60; itb += 3) {
    body(itb + 0, 0, 2, 0);
    body(itb + 1, 1, 0, 0);
    body(itb + 2, 2, 1, 0);
  }
  body(60, 0, 2, 0);
  body(61, 1, 0, 0);
  body(62, 2, 1, 1);
  body(63, 0, 2, 2);

#pragma unroll
  for (int mf = 0; mf < 2; ++mf) {
    int row = n0 + wm * 32 + mf * 16 + kg * 4;
    f32x4 dr = *(const f32x4*)&dnorm[b * NDIM + row];
#pragma unroll
    for (int nf = 0; nf < 4; ++nf) {
      int col = wn * 64 + nf * 16 + lr;
      float bv = bias[col];
      float* op = out + ((size_t)b * NDIM + row) * FDIM + col;
#pragma unroll
      for (int j = 0; j < 4; ++j) op[(size_t)j * FDIM] = dr[j] * acc[mf][nf][j] + bv;
    }
  }
}

extern "C" void kernel_launch(void* const* d_in, const int* in_sizes, int n_in,
                              void* d_out, int out_size, void* d_ws, size_t ws_size,
                              hipStream_t stream) {
  (void)in_sizes; (void)n_in; (void)out_size; (void)ws_size;
  const float* input = (const float*)d_in[0];
  const float* adj = (const float*)d_in[1];
  const float* weight = (const float*)d_in[2];
  const float* bias = (const float*)d_in[3];
  float* out = (float*)d_out;

  char* ws = (char*)d_ws;
  short* st = (short*)ws;                                       // 8 MB  (bf16 S^T)
  float* dnorm = (float*)(ws + 8ull * 1024 * 1024);             // 64 KB
  float* part = (float*)(ws + 8ull * 1024 * 1024 + 65536);      // 2 MB
  short* wt = (short*)(ws + 8ull * 1024 * 1024 + 65536 + 2ull * 1024 * 1024);  // 128 KB

  k_colsum<<<dim3(528), dim3(256), 0, stream>>>(adj, part, weight, wt);
  k_support<<<dim3(BATCH * (NDIM / 64)), dim3(512), 0, stream>>>(input, wt, part, dnorm, st);
  k_main<<<dim3(BATCH * (NDIM / 64)), dim3(512), 0, stream>>>(adj, st, dnorm, bias, out);
}

// Round 16
// 70.408 us; speedup vs baseline: 1.2406x; 1.2406x over previous
//
#include <hip/hip_runtime.h>
#include <hip/hip_bf16.h>

#define BATCH 8
#define NDIM 2048
#define FDIM 256
#define CH 32   // row-chunks for column-sum partials (64 rows each)

typedef float f32x4 __attribute__((ext_vector_type(4)));
typedef short bf16x8 __attribute__((ext_vector_type(8)));
typedef short bf16x4 __attribute__((ext_vector_type(4)));

// hardware RNE convert (lowers to v_cvt_pk_bf16_f32 when paired)
__device__ __forceinline__ short f2bf(float f) {
  __hip_bfloat16 h = __float2bfloat16(f);
  short s;
  __builtin_memcpy(&s, &h, 2);
  return s;
}

__device__ __forceinline__ void gload_lds16(const void* g, void* l) {
  __builtin_amdgcn_global_load_lds(
      (const __attribute__((address_space(1))) void*)g,
      (__attribute__((address_space(3))) void*)l, 16, 0, 0);
}

// A-tile source-chunk swizzle (f32 rows of 16 chunks x 16B):
// LDS[r][c] holds G[r][2*((c>>1)^(r&7)) + ((c&1)^((r>>3)&1))]  (involution)
// Read side: G-chunk 2gk   lives at c = 2*(gk^(r&7)) + ((r>>3)&1)
//            G-chunk 2gk+1 lives at c = 2*(gk^(r&7)) + (((r>>3)&1)^1)
// (no further fixup needed — the low-bit XOR is self-compensating)
__device__ __forceinline__ int aswz(int c, int r) {
  return 2 * ((c >> 1) ^ (r & 7)) + ((c & 1) ^ ((r >> 3) & 1));
}

// ---- Kernel 1: colsum partials (blocks 0..511) + Wt transpose (512..527) --
__global__ __launch_bounds__(256) void k_colsum(const float* __restrict__ adj,
                                                float* __restrict__ part,
                                                const float* __restrict__ w,
                                                short* __restrict__ wt) {
  int bid = blockIdx.x;
  int t = threadIdx.x;
  if (bid < 512) {
    int cb = bid & 1;
    int ch = (bid >> 1) & (CH - 1);
    int b = bid >> 6;
    int col = cb * 1024 + t * 4;
    const float* p = adj + (size_t)b * NDIM * NDIM + (size_t)(ch * 64) * NDIM + col;
    f32x4 acc = {0.f, 0.f, 0.f, 0.f};
#pragma unroll 8
    for (int i = 0; i < 64; ++i) acc += *(const f32x4*)(p + (size_t)i * NDIM);
    *(f32x4*)(part + (size_t)(b * CH + ch) * NDIM + col) = acc;
  } else {
    __shared__ float tile[64][65];
    int bb = bid - 512;
    int bx = bb & 3, by = bb >> 2;
    int f0 = by * 64, o0 = bx * 64;
    int c4 = 4 * (t & 15);
#pragma unroll
    for (int q = 0; q < 4; ++q) {
      int r = (t >> 4) + 16 * q;
      f32x4 v = *(const f32x4*)(w + (size_t)(f0 + r) * FDIM + o0 + c4);
#pragma unroll
      for (int i = 0; i < 4; ++i) tile[r][c4 + i] = v[i];
    }
    __syncthreads();
#pragma unroll
    for (int q = 0; q < 4; ++q) {
      int r = (t >> 4) + 16 * q;
      bf16x4 pk;
#pragma unroll
      for (int i = 0; i < 4; ++i) pk[i] = f2bf(tile[c4 + i][r]);
      *(bf16x4*)(wt + (size_t)(o0 + r) * FDIM + f0 + c4) = pk;
    }
  }
}

// ---- Kernel 2: St[b][o][m] = bf16(d[b][m] * (X @ W)[m][o]) ----
__global__ __launch_bounds__(512) void k_support(const float* __restrict__ in,
                                                 const short* __restrict__ wt,
                                                 const float* __restrict__ part,
                                                 float* __restrict__ dnorm,
                                                 short* __restrict__ st) {
  __shared__ float Alf[3][64 * 64];   // 3 x 16 KB (f32 A tiles)
  __shared__ short Bl[3][256 * 64];   // 3 x 32 KB (bf16 B tiles)
  __shared__ float dnLds[64];
  int t = threadIdx.x, lane = t & 63, w = t >> 6;
  int wm = w & 1, wn = w >> 1;
  int b = blockIdx.x & 7;
  int m0 = (blockIdx.x >> 3) * 64;
  const float* inb = in + ((size_t)b * NDIM + m0) * FDIM;

  if (t < 64) {
    float s = 0.f;
#pragma unroll
    for (int c = 0; c < CH; ++c) s += part[(size_t)(b * CH + c) * NDIM + m0 + t];
    float dv = rsqrtf(s);
    dnLds[t] = dv;
    dnorm[b * NDIM + m0 + t] = dv;
  }
  asm volatile("s_waitcnt vmcnt(0)" ::: "memory");

  int s0 = t, s1 = 512 + t;
  int r0 = s0 >> 4, c0 = aswz(s0 & 15, r0);
  int r1 = s1 >> 4, c1 = aswz(s1 & 15, r1);
  const float* a0s = inb + (size_t)r0 * FDIM + c0 * 4;
  const float* a1s = inb + (size_t)r1 * FDIM + c1 * 4;
  int arow = t >> 3;
  int schk = (t & 7) ^ (arow & 7);
  const short* bsrc = wt + (size_t)arow * FDIM + 8 * schk;

  f32x4 acc[2][4];
#pragma unroll
  for (int m = 0; m < 2; ++m)
#pragma unroll
    for (int n = 0; n < 4; ++n) acc[m][n] = {0.f, 0.f, 0.f, 0.f};

  int lr = lane & 15, kg = lane >> 4, sw = lane & 7;
  int bA = (lr >> 3) & 1;

  auto stage = [&](int k, int bp) {
    size_t ko = (size_t)k * 64;
    gload_lds16(a0s + ko, &Alf[bp][s0 * 4]);
    gload_lds16(a1s + ko, &Alf[bp][s1 * 4]);
#pragma unroll
    for (int i = 0; i < 4; ++i)
      gload_lds16(bsrc + (size_t)(i * 64) * FDIM + ko, &Bl[bp][(i * 512 + t) * 8]);
  };

  auto body = [&](int it, int bc, int bp, int mode) {
    if (mode == 0) {
      stage(it + 2, bp);
      asm volatile("s_waitcnt vmcnt(12)" ::: "memory");
    } else if (mode == 1) {
      asm volatile("s_waitcnt vmcnt(6)" ::: "memory");
    } else {
      asm volatile("s_waitcnt vmcnt(0)" ::: "memory");
    }
    __builtin_amdgcn_s_barrier();
    asm volatile("" ::: "memory");
    __builtin_amdgcn_sched_barrier(0);
#pragma unroll
    for (int h = 0; h < 2; ++h) {
      int gk = h * 4 + kg;
      int p2 = 2 * (gk ^ sw);
      bf16x8 af[2];
#pragma unroll
      for (int mf = 0; mf < 2; ++mf) {
        int row = wm * 32 + mf * 16 + lr;
        f32x4 lo = *(const f32x4*)&Alf[bc][row * 64 + (p2 + bA) * 4];
        f32x4 hi = *(const f32x4*)&Alf[bc][row * 64 + (p2 + (bA ^ 1)) * 4];
#pragma unroll
        for (int j = 0; j < 4; ++j) { af[mf][j] = f2bf(lo[j]); af[mf][4 + j] = f2bf(hi[j]); }
      }
      int kc = (gk ^ sw) * 8;
      bf16x8 bv0 = *(const bf16x8*)&Bl[bc][(wn * 64 + lr) * 64 + kc];
      bf16x8 bv1 = *(const bf16x8*)&Bl[bc][(wn * 64 + 16 + lr) * 64 + kc];
      bf16x8 bv2 = *(const bf16x8*)&Bl[bc][(wn * 64 + 32 + lr) * 64 + kc];
      bf16x8 bv3 = *(const bf16x8*)&Bl[bc][(wn * 64 + 48 + lr) * 64 + kc];
      acc[0][0] = __builtin_amdgcn_mfma_f32_16x16x32_bf16(af[0], bv0, acc[0][0], 0, 0, 0);
      acc[0][1] = __builtin_amdgcn_mfma_f32_16x16x32_bf16(af[0], bv1, acc[0][1], 0, 0, 0);
      acc[0][2] = __builtin_amdgcn_mfma_f32_16x16x32_bf16(af[0], bv2, acc[0][2], 0, 0, 0);
      acc[0][3] = __builtin_amdgcn_mfma_f32_16x16x32_bf16(af[0], bv3, acc[0][3], 0, 0, 0);
      acc[1][0] = __builtin_amdgcn_mfma_f32_16x16x32_bf16(af[1], bv0, acc[1][0], 0, 0, 0);
      acc[1][1] = __builtin_amdgcn_mfma_f32_16x16x32_bf16(af[1], bv1, acc[1][1], 0, 0, 0);
      acc[1][2] = __builtin_amdgcn_mfma_f32_16x16x32_bf16(af[1], bv2, acc[1][2], 0, 0, 0);
      acc[1][3] = __builtin_amdgcn_mfma_f32_16x16x32_bf16(af[1], bv3, acc[1][3], 0, 0, 0);
    }
    asm volatile("s_waitcnt lgkmcnt(0)" ::: "memory");
    __builtin_amdgcn_s_barrier();
    asm volatile("" ::: "memory");
  };

  stage(0, 0);
  stage(1, 1);
  body(0, 0, 2, 0);
  body(1, 1, 0, 0);
  body(2, 2, 1, 1);
  body(3, 0, 2, 2);

#pragma unroll
  for (int mf = 0; mf < 2; ++mf) {
    int rloc = wm * 32 + mf * 16 + kg * 4;
    int row = m0 + rloc;
    float dm[4];
#pragma unroll
    for (int j = 0; j < 4; ++j) dm[j] = dnLds[rloc + j];
#pragma unroll
    for (int nf = 0; nf < 4; ++nf) {
      int col = wn * 64 + nf * 16 + lr;
      bf16x4 pk;
#pragma unroll
      for (int j = 0; j < 4; ++j) pk[j] = f2bf(acc[mf][nf][j] * dm[j]);
      *(bf16x4*)(st + ((size_t)(b * FDIM + col)) * NDIM + row) = pk;
    }
  }
}

// ---- Kernel 3: out = d_n * (adj @ St^T) + bias ----
__global__ __launch_bounds__(512) void k_main(const float* __restrict__ adj,
                                              const short* __restrict__ st,
                                              const float* __restrict__ dnorm,
                                              const float* __restrict__ bias,
                                              float* __restrict__ out) {
  __shared__ float Alf[3][64 * 64];   // 3 x 16 KB (f32 A tiles)
  __shared__ short Bl[3][256 * 64];   // 3 x 32 KB (bf16 B tiles)
  int t = threadIdx.x, lane = t & 63, w = t >> 6;
  int wm = w & 1, wn = w >> 1;
  int b = blockIdx.x & 7;
  int n0 = (blockIdx.x >> 3) * 64;
  const float* ab = adj + ((size_t)b * NDIM + n0) * NDIM;
  const short* stb = st + (size_t)b * FDIM * NDIM;

  int s0 = t, s1 = 512 + t;
  int r0 = s0 >> 4, c0 = aswz(s0 & 15, r0);
  int r1 = s1 >> 4, c1 = aswz(s1 & 15, r1);
  const float* a0s = ab + (size_t)r0 * NDIM + c0 * 4;
  const float* a1s = ab + (size_t)r1 * NDIM + c1 * 4;
  int arow = t >> 3;
  int schk = (t & 7) ^ (arow & 7);
  const short* bsrc = stb + (size_t)arow * NDIM + 8 * schk;

  f32x4 acc[2][4];
#pragma unroll
  for (int m = 0; m < 2; ++m)
#pragma unroll
    for (int n = 0; n < 4; ++n) acc[m][n] = {0.f, 0.f, 0.f, 0.f};

  int lr = lane & 15, kg = lane >> 4, sw = lane & 7;
  int bA = (lr >> 3) & 1;

  auto stage = [&](int k, int bp) {
    size_t ko = (size_t)k * 64;
    gload_lds16(a0s + ko, &Alf[bp][s0 * 4]);
    gload_lds16(a1s + ko, &Alf[bp][s1 * 4]);
#pragma unroll
    for (int i = 0; i < 4; ++i)
      gload_lds16(bsrc + (size_t)(i * 64) * NDIM + ko, &Bl[bp][(i * 512 + t) * 8]);
  };

  auto body = [&](int it, int bc, int bp, int mode) {
    if (mode == 0) {
      stage(it + 2, bp);
      asm volatile("s_waitcnt vmcnt(12)" ::: "memory");
    } else if (mode == 1) {
      asm volatile("s_waitcnt vmcnt(6)" ::: "memory");
    } else {
      asm volatile("s_waitcnt vmcnt(0)" ::: "memory");
    }
    __builtin_amdgcn_s_barrier();
    asm volatile("" ::: "memory");
    __builtin_amdgcn_sched_barrier(0);
#pragma unroll
    for (int h = 0; h < 2; ++h) {
      int gk = h * 4 + kg;
      int p2 = 2 * (gk ^ sw);
      bf16x8 af[2];
#pragma unroll
      for (int mf = 0; mf < 2; ++mf) {
        int row = wm * 32 + mf * 16 + lr;
        f32x4 lo = *(const f32x4*)&Alf[bc][row * 64 + (p2 + bA) * 4];
        f32x4 hi = *(const f32x4*)&Alf[bc][row * 64 + (p2 + (bA ^ 1)) * 4];
#pragma unroll
        for (int j = 0; j < 4; ++j) { af[mf][j] = f2bf(lo[j]); af[mf][4 + j] = f2bf(hi[j]); }
      }
      int kc = (gk ^ sw) * 8;
      bf16x8 bv0 = *(const bf16x8*)&Bl[bc][(wn * 64 + lr) * 64 + kc];
      bf16x8 bv1 = *(const bf16x8*)&Bl[bc][(wn * 64 + 16 + lr) * 64 + kc];
      bf16x8 bv2 = *(const bf16x8*)&Bl[bc][(wn * 64 + 32 + lr) * 64 + kc];
      bf16x8 bv3 = *(const bf16x8*)&Bl[bc][(wn * 64 + 48 + lr) * 64 + kc];
      acc[0][0] = __builtin_amdgcn_mfma_f32_16x16x32_bf16(af[0], bv0, acc[0][0], 0, 0, 0);
      acc[0][1] = __builtin_amdgcn_mfma_f32_16x16x32_bf16(af[0], bv1, acc[0][1], 0, 0, 0);
      acc[0][2] = __builtin_amdgcn_mfma_f32_16x16x32_bf16(af[0], bv2, acc[0][2], 0, 0, 0);
      acc[0][3] = __builtin_amdgcn_mfma_f32_16x16x32_bf16(af[0], bv3, acc[0][3], 0, 0, 0);
      acc[1][0] = __builtin_amdgcn_mfma_f32_16x16x32_bf16(af[1], bv0, acc[1][0], 0, 0, 0);
      acc[1][1] = __builtin_amdgcn_mfma_f32_16x16x32_bf16(af[1], bv1, acc[1][1], 0, 0, 0);
      acc[1][2] = __builtin_amdgcn_mfma_f32_16x16x32_bf16(af[1], bv2, acc[1][2], 0, 0, 0);
      acc[1][3] = __builtin_amdgcn_mfma_f32_16x16x32_bf16(af[1], bv3, acc[1][3], 0, 0, 0);
    }
    asm volatile("s_waitcnt lgkmcnt(0)" ::: "memory");
    __builtin_amdgcn_s_barrier();
    asm volatile("" ::: "memory");
  };

  stage(0, 0);
  stage(1, 1);
  for (int itb = 0; itb < 30; itb += 3) {
    body(itb + 0, 0, 2, 0);
    body(itb + 1, 1, 0, 0);
    body(itb + 2, 2, 1, 0);
  }
  body(30, 0, 2, 1);
  body(31, 1, 0, 2);

#pragma unroll
  for (int mf = 0; mf < 2; ++mf) {
    int row = n0 + wm * 32 + mf * 16 + kg * 4;
    f32x4 dr = *(const f32x4*)&dnorm[b * NDIM + row];
#pragma unroll
    for (int nf = 0; nf < 4; ++nf) {
      int col = wn * 64 + nf * 16 + lr;
      float bv = bias[col];
      float* op = out + ((size_t)b * NDIM + row) * FDIM + col;
#pragma unroll
      for (int j = 0; j < 4; ++j) op[(size_t)j * FDIM] = dr[j] * acc[mf][nf][j] + bv;
    }
  }
}

extern "C" void kernel_launch(void* const* d_in, const int* in_sizes, int n_in,
                              void* d_out, int out_size, void* d_ws, size_t ws_size,
                              hipStream_t stream) {
  (void)in_sizes; (void)n_in; (void)out_size; (void)ws_size;
  const float* input = (const float*)d_in[0];
  const float* adj = (const float*)d_in[1];
  const float* weight = (const float*)d_in[2];
  const float* bias = (const float*)d_in[3];
  float* out = (float*)d_out;

  char* ws = (char*)d_ws;
  short* st = (short*)ws;                                       // 8 MB  (bf16 S^T)
  float* dnorm = (float*)(ws + 8ull * 1024 * 1024);             // 64 KB
  float* part = (float*)(ws + 8ull * 1024 * 1024 + 65536);      // 2 MB
  short* wt = (short*)(ws + 8ull * 1024 * 1024 + 65536 + 2ull * 1024 * 1024);  // 128 KB

  k_colsum<<<dim3(528), dim3(256), 0, stream>>>(adj, part, weight, wt);
  k_support<<<dim3(BATCH * (NDIM / 64)), dim3(512), 0, stream>>>(input, wt, part, dnorm, st);
  k_main<<<dim3(BATCH * (NDIM / 64)), dim3(512), 0, stream>>>(adj, st, dnorm, bias, out);
}